// Round 1
// baseline (707.637 us; speedup 1.0000x reference)
//
#include <hip/hip_runtime.h>
#include <math.h>

// Problem constants
#define K_  32
#define HN  16      // n/2
#define N_  32
#define M_  128
#define B_  8
#define T_  2048
#define D_  128
#define BT  (B_*T_)     // 16384
#define KA  1056        // GEMM K: 512 Re(s) + 512 Im(s) + 32 xp

// ---------------------------------------------------------------------------
// K1: lambda (j<16) and Bp (j<16) via direct complex product.
// Bp[k,j] = 1 / prod_{i != j} (1 - lam_i/lam_j),  lam_i on unit circle so
// lam_i/lam_j = exp(i*(ang_i - ang_j)).
// ws layout (floats): [0..512) lamRe, [512..1024) lamIm,
//                     [1024..1536) BpRe, [1536..2048) BpIm
// ---------------------------------------------------------------------------
__global__ void k_lambp(const float* __restrict__ theta, float* __restrict__ ws) {
    int tid = threadIdx.x;            // 512 threads: k*16 + j
    int k = tid >> 4, j = tid & 15;
    float angj = theta[k * HN + j];
    float pr = 1.f, pi = 0.f;
    for (int i = 0; i < N_; ++i) {
        if (i == j) continue;
        float angi = (i < HN) ? theta[k * HN + i] : -theta[k * HN + i - HN];
        float d = angi - angj;
        float tr = 1.f - cosf(d);
        float ti = -sinf(d);
        float nr = pr * tr - pi * ti;
        float ni = pr * ti + pi * tr;
        pr = nr; pi = ni;
    }
    float den = pr * pr + pi * pi;
    ws[tid]        = cosf(angj);
    ws[512 + tid]  = sinf(angj);
    ws[1024 + tid] = pr / den;        // Re(1/p) = conj(p)/|p|^2
    ws[1536 + tid] = -pi / den;
}

// ---------------------------------------------------------------------------
// K2: build GEMM weight matrix W [1056 x 128].
//  c = k*16+j        : (ReCp[k,j,m] + ReCp[k,j+16,m]) / 32
//  c = 512 + k*16+j  : (ImCp[k,j+16,m] - ImCp[k,j,m]) / 32
//  c = 1024 + k      : D[k,m] / 32
// Cp = exp(lnC_r) * (cos(lnC_i) + i sin(lnC_i))
// ---------------------------------------------------------------------------
__global__ void k_weights(const float* __restrict__ lnC_r,
                          const float* __restrict__ lnC_i,
                          const float* __restrict__ D,
                          float* __restrict__ W) {
    int t = blockIdx.x * blockDim.x + threadIdx.x;
    const float inv = 1.f / 32.f;
    if (t < K_ * HN * M_) {                 // 65536
        int m = t & 127, j = (t >> 7) & 15, k = t >> 11;
        int i0 = (k * N_ + j) * M_ + m;
        int i1 = (k * N_ + j + HN) * M_ + m;
        float r0 = expf(lnC_r[i0]), c0 = cosf(lnC_i[i0]), s0 = sinf(lnC_i[i0]);
        float r1 = expf(lnC_r[i1]), c1 = cosf(lnC_i[i1]), s1 = sinf(lnC_i[i1]);
        W[(k * 16 + j) * M_ + m]       = (r0 * c0 + r1 * c1) * inv;
        W[(512 + k * 16 + j) * M_ + m] = (r1 * s1 - r0 * s0) * inv;
    } else if (t < K_ * HN * M_ + K_ * M_) {
        int u = t - K_ * HN * M_;
        int m = u & 127, k = u >> 7;
        W[(1024 + k) * M_ + m] = D[k * M_ + m] * inv;
    }
}

// ---------------------------------------------------------------------------
// K3: xp[b,t,k] = sum_d x[b,t,d]*R[d,k]; also scatter into A cols 1024..1055.
// block: 256 thr = 32 k-lanes x 8 rows; grid 2048.
// ---------------------------------------------------------------------------
__global__ __launch_bounds__(256) void k_xp(const float* __restrict__ x,
                                            const float* __restrict__ R,
                                            float* __restrict__ xp,
                                            float* __restrict__ A) {
    int kk = threadIdx.x & 31;
    int r8 = threadIdx.x >> 5;
    int row = blockIdx.x * 8 + r8;          // row = b*T + t
    const float* xr = x + (size_t)row * D_;
    float acc = 0.f;
    #pragma unroll 8
    for (int i = 0; i < D_; ++i) acc += xr[i] * R[i * K_ + kk];
    xp[row * K_ + kk] = acc;
    int b = row >> 11, tt = row & 2047;
    A[(size_t)(tt * 8 + b) * KA + 1024 + kk] = acc;
}

// ---------------------------------------------------------------------------
// K4: sequential scan. s_t = lam*s_{t-1} + Bp*xp[t-1], s_0 = 0 (shifted).
// Writes Re(s) to A col (k*16+j), Im(s) to col 512+(k*16+j), row = t*8+b.
// grid 64 = 8 b x 8 kgroups; block 64 thr = 4 k x 16 j.
// ---------------------------------------------------------------------------
__global__ __launch_bounds__(64) void k_scan(const float* __restrict__ xp,
                                             const float* __restrict__ ws,
                                             float* __restrict__ A) {
    int b  = blockIdx.x & 7;
    int kg = blockIdx.x >> 3;
    int j  = threadIdx.x & 15;
    int k  = kg * 4 + (threadIdx.x >> 4);
    int c  = k * 16 + j;
    float lr = ws[c], li = ws[512 + c], br = ws[1024 + c], bi = ws[1536 + c];
    float sr = 0.f, si = 0.f;
    const float* xpb = xp + (size_t)b * T_ * K_ + k;
    float* Ab = A + (size_t)b * KA + c;
    for (int t = 0; t < T_; ++t) {
        if (t > 0) {
            float xv = xpb[(t - 1) * K_];
            float nr = br * xv + lr * sr - li * si;
            float ni = bi * xv + lr * si + li * sr;
            sr = nr; si = ni;
        }
        Ab[0]   = sr;
        Ab[512] = si;
        Ab += 8 * KA;
    }
}

// ---------------------------------------------------------------------------
// K5: out[(b*T+t)*128 + m] = sum_c A[(t*8+b), c] * W[c, m] + Do[m]
// Tiled fp32 GEMM: BM=64, BN=128(full), BK=32; 256 blocks x 256 thr;
// per-thread 4 rows x 8 cols.
// ---------------------------------------------------------------------------
#define BM 64
#define BK 32
__global__ __launch_bounds__(256) void k_gemm(const float* __restrict__ A,
                                              const float* __restrict__ W,
                                              const float* __restrict__ Do,
                                              float* __restrict__ out) {
    __shared__ float As[BM * 33];     // +1 pad
    __shared__ float Ws[BK * M_];
    int tid = threadIdx.x;
    int rl = tid & 15;                // row lane
    int cl = tid >> 4;                // col lane: cols cl*8..cl*8+7
    int row0 = blockIdx.x * BM;

    float acc[4][8];
    #pragma unroll
    for (int i = 0; i < 4; ++i)
        #pragma unroll
        for (int jj = 0; jj < 8; ++jj) acc[i][jj] = 0.f;

    for (int k0 = 0; k0 < KA; k0 += BK) {
        // A tile: 64x32 = 2048 floats, 8 per thread
        {
            int arow = tid >> 2;
            int acol = (tid & 3) * 8;
            const float* src = A + (size_t)(row0 + arow) * KA + k0 + acol;
            float* dst = As + arow * 33 + acol;
            float4 v0 = *(const float4*)(src);
            float4 v1 = *(const float4*)(src + 4);
            dst[0] = v0.x; dst[1] = v0.y; dst[2] = v0.z; dst[3] = v0.w;
            dst[4] = v1.x; dst[5] = v1.y; dst[6] = v1.z; dst[7] = v1.w;
        }
        // W tile: 32x128 = 4096 floats, 16 per thread
        {
            int idx = tid * 16;
            int wrow = idx >> 7;
            int wcol = idx & 127;
            const float* src = W + (size_t)(k0 + wrow) * M_ + wcol;
            float* dst = Ws + wrow * M_ + wcol;
            #pragma unroll
            for (int u = 0; u < 16; u += 4)
                *(float4*)(dst + u) = *(const float4*)(src + u);
        }
        __syncthreads();
        #pragma unroll 4
        for (int kk = 0; kk < BK; ++kk) {
            float a[4], w[8];
            #pragma unroll
            for (int i = 0; i < 4; ++i) a[i] = As[(rl + 16 * i) * 33 + kk];
            float4 w0 = *(const float4*)(Ws + kk * M_ + cl * 8);
            float4 w1 = *(const float4*)(Ws + kk * M_ + cl * 8 + 4);
            w[0]=w0.x; w[1]=w0.y; w[2]=w0.z; w[3]=w0.w;
            w[4]=w1.x; w[5]=w1.y; w[6]=w1.z; w[7]=w1.w;
            #pragma unroll
            for (int i = 0; i < 4; ++i)
                #pragma unroll
                for (int jj = 0; jj < 8; ++jj) acc[i][jj] += a[i] * w[jj];
        }
        __syncthreads();
    }

    float dov[8];
    #pragma unroll
    for (int u = 0; u < 8; ++u) dov[u] = Do[cl * 8 + u];

    #pragma unroll
    for (int i = 0; i < 4; ++i) {
        int r = row0 + rl + 16 * i;
        int b = r & 7, t = r >> 3;
        float* o = out + ((size_t)(b * T_ + t)) * M_ + cl * 8;
        float4 s0, s1;
        s0.x = acc[i][0] + dov[0]; s0.y = acc[i][1] + dov[1];
        s0.z = acc[i][2] + dov[2]; s0.w = acc[i][3] + dov[3];
        s1.x = acc[i][4] + dov[4]; s1.y = acc[i][5] + dov[5];
        s1.z = acc[i][6] + dov[6]; s1.w = acc[i][7] + dov[7];
        *(float4*)(o) = s0;
        *(float4*)(o + 4) = s1;
    }
}

// ---------------------------------------------------------------------------
extern "C" void kernel_launch(void* const* d_in, const int* in_sizes, int n_in,
                              void* d_out, int out_size, void* d_ws, size_t ws_size,
                              hipStream_t stream) {
    const float* x     = (const float*)d_in[0];
    const float* R     = (const float*)d_in[1];
    const float* theta = (const float*)d_in[2];
    const float* lnC_r = (const float*)d_in[3];
    const float* lnC_i = (const float*)d_in[4];
    const float* D     = (const float*)d_in[5];
    const float* Do    = (const float*)d_in[6];
    float* out = (float*)d_out;

    float* wsf   = (float*)d_ws;
    float* lambp = wsf;                        // 2048 floats
    float* W     = wsf + 2048;                 // 1056*128 = 135168
    float* xp    = W + (size_t)KA * M_;        // 16384*32 = 524288
    float* A     = xp + (size_t)BT * K_;       // 16384*1056 = 17301504

    k_lambp<<<1, 512, 0, stream>>>(theta, lambp);
    k_weights<<<272, 256, 0, stream>>>(lnC_r, lnC_i, D, W);
    k_xp<<<BT / 8, 256, 0, stream>>>(x, R, xp, A);
    k_scan<<<64, 64, 0, stream>>>(xp, lambp, A);
    k_gemm<<<BT / BM, 256, 0, stream>>>(A, W, Do, out);
}

// Round 2
// 247.804 us; speedup vs baseline: 2.8556x; 2.8556x over previous
//
#include <hip/hip_runtime.h>
#include <math.h>

// Problem constants
#define K_  32
#define HN  16      // n/2
#define N_  32
#define M_  128
#define B_  8
#define T_  2048
#define D_  128
#define BT  (B_*T_)     // 16384
#define KA  1056        // GEMM K: 512 Re(s) + 512 Im(s) + 32 xp
#define CHK 32          // chunks per series
#define CL  64          // chunk length (T/CHK)
#define NSER (B_*K_*HN) // 4096 series
#define NSC  (NSER*CHK) // 131072 series-chunks

// ---------------------------------------------------------------------------
// K1: lambda (j<16) and Bp (j<16) via direct complex product.
// ws layout (floats): [0..512) lamRe, [512..1024) lamIm,
//                     [1024..1536) BpRe, [1536..2048) BpIm
// ---------------------------------------------------------------------------
__global__ void k_lambp(const float* __restrict__ theta, float* __restrict__ ws) {
    int tid = threadIdx.x;            // 512 threads: k*16 + j
    int k = tid >> 4, j = tid & 15;
    float angj = theta[k * HN + j];
    float pr = 1.f, pi = 0.f;
    for (int i = 0; i < N_; ++i) {
        if (i == j) continue;
        float angi = (i < HN) ? theta[k * HN + i] : -theta[k * HN + i - HN];
        float d = angi - angj;
        float tr = 1.f - cosf(d);
        float ti = -sinf(d);
        float nr = pr * tr - pi * ti;
        float ni = pr * ti + pi * tr;
        pr = nr; pi = ni;
    }
    float den = pr * pr + pi * pi;
    ws[tid]        = cosf(angj);
    ws[512 + tid]  = sinf(angj);
    ws[1024 + tid] = pr / den;        // Re(1/p) = conj(p)/|p|^2
    ws[1536 + tid] = -pi / den;
}

// ---------------------------------------------------------------------------
// K2: build GEMM weight matrix W [1056 x 128].
// ---------------------------------------------------------------------------
__global__ void k_weights(const float* __restrict__ lnC_r,
                          const float* __restrict__ lnC_i,
                          const float* __restrict__ D,
                          float* __restrict__ W) {
    int t = blockIdx.x * blockDim.x + threadIdx.x;
    const float inv = 1.f / 32.f;
    if (t < K_ * HN * M_) {                 // 65536
        int m = t & 127, j = (t >> 7) & 15, k = t >> 11;
        int i0 = (k * N_ + j) * M_ + m;
        int i1 = (k * N_ + j + HN) * M_ + m;
        float r0 = expf(lnC_r[i0]), c0 = cosf(lnC_i[i0]), s0 = sinf(lnC_i[i0]);
        float r1 = expf(lnC_r[i1]), c1 = cosf(lnC_i[i1]), s1 = sinf(lnC_i[i1]);
        W[(k * 16 + j) * M_ + m]       = (r0 * c0 + r1 * c1) * inv;
        W[(512 + k * 16 + j) * M_ + m] = (r1 * s1 - r0 * s0) * inv;
    } else if (t < K_ * HN * M_ + K_ * M_) {
        int u = t - K_ * HN * M_;
        int m = u & 127, k = u >> 7;
        W[(1024 + k) * M_ + m] = D[k * M_ + m] * inv;
    }
}

// ---------------------------------------------------------------------------
// K3: xp[b,t,k] = sum_d x[b,t,d]*R[d,k]; also scatter into A cols 1024..1055.
// ---------------------------------------------------------------------------
__global__ __launch_bounds__(256) void k_xp(const float* __restrict__ x,
                                            const float* __restrict__ R,
                                            float* __restrict__ xp,
                                            float* __restrict__ A) {
    int kk = threadIdx.x & 31;
    int r8 = threadIdx.x >> 5;
    int row = blockIdx.x * 8 + r8;          // row = b*T + t
    const float* xr = x + (size_t)row * D_;
    float acc = 0.f;
    #pragma unroll 8
    for (int i = 0; i < D_; ++i) acc += xr[i] * R[i * K_ + kk];
    xp[row * K_ + kk] = acc;
    int b = row >> 11, tt = row & 2047;
    A[(size_t)(tt * 8 + b) * KA + 1024 + kk] = acc;
}

// ---------------------------------------------------------------------------
// K4a: per-chunk local end-state. Thread = (b,k,c,j); 131072 threads.
// E layout: E[(((b*32+k)*32+c)*16+j)]  (Re), +131072 (Im)
// ---------------------------------------------------------------------------
__global__ __launch_bounds__(256) void k_scan_ends(const float* __restrict__ xp,
                                                   const float* __restrict__ ws,
                                                   float* __restrict__ E) {
    int gid = blockIdx.x * 256 + threadIdx.x;
    int j = gid & 15, c = (gid >> 4) & 31, k = (gid >> 9) & 31, b = gid >> 14;
    int col = k * 16 + j;
    float lr = ws[col], li = ws[512 + col], br = ws[1024 + col], bi = ws[1536 + col];
    float sr = 0.f, si = 0.f;
    const float* xpb = xp + (size_t)b * T_ * K_ + k;
    int t0 = c * CL;
    for (int p = 0; p < CL; ++p) {
        int t = t0 + p;
        if (t > 0) {
            float xv = xpb[(t - 1) * K_];
            float nr = br * xv + lr * sr - li * si;
            float ni = bi * xv + lr * si + li * sr;
            sr = nr; si = ni;
        }
    }
    size_t eidx = ((size_t)(b * 32 + k) * 32 + c) * 16 + j;
    E[eidx] = sr;
    E[NSC + eidx] = si;
}

// ---------------------------------------------------------------------------
// K4b: exclusive-prefix carries per series. S_c_excl = s_{t0-1} (global).
// 4096 threads; 32-step sequential combine with lambda^64.
// ---------------------------------------------------------------------------
__global__ void k_carries(const float* __restrict__ ws,
                          const float* __restrict__ E,
                          float* __restrict__ S) {
    int tid = blockIdx.x * blockDim.x + threadIdx.x;   // 4096
    int j = tid & 15, k = (tid >> 4) & 31, b = tid >> 9;
    int col = k * 16 + j;
    float lr = ws[col], li = ws[512 + col];
    float pr = lr, pi = li;                 // lambda^64 via 6 squarings
    #pragma unroll
    for (int q = 0; q < 6; ++q) {
        float nr = pr * pr - pi * pi;
        float ni = 2.f * pr * pi;
        pr = nr; pi = ni;
    }
    float sr = 0.f, si = 0.f;
    size_t base = (size_t)(b * 32 + k) * 32 * 16 + j;
    for (int c = 0; c < CHK; ++c) {
        size_t idx = base + (size_t)c * 16;
        S[idx] = sr;
        S[NSC + idx] = si;
        float er = E[idx], ei = E[NSC + idx];
        float nr = pr * sr - pi * si + er;
        float ni = pr * si + pi * sr + ei;
        sr = nr; si = ni;
    }
}

// ---------------------------------------------------------------------------
// K4c: final chunk scan seeded with carry; writes Re/Im into A.
// Same thread mapping as K4a.
// ---------------------------------------------------------------------------
__global__ __launch_bounds__(256) void k_scan_write(const float* __restrict__ xp,
                                                    const float* __restrict__ ws,
                                                    const float* __restrict__ S,
                                                    float* __restrict__ A) {
    int gid = blockIdx.x * 256 + threadIdx.x;
    int j = gid & 15, c = (gid >> 4) & 31, k = (gid >> 9) & 31, b = gid >> 14;
    int col = k * 16 + j;
    float lr = ws[col], li = ws[512 + col], br = ws[1024 + col], bi = ws[1536 + col];
    size_t sidx = ((size_t)(b * 32 + k) * 32 + c) * 16 + j;
    float sr = S[sidx], si = S[NSC + sidx];
    const float* xpb = xp + (size_t)b * T_ * K_ + k;
    int t0 = c * CL;
    float* Ab = A + (size_t)(t0 * 8 + b) * KA + col;
    for (int p = 0; p < CL; ++p) {
        int t = t0 + p;
        if (t > 0) {
            float xv = xpb[(t - 1) * K_];
            float nr = br * xv + lr * sr - li * si;
            float ni = bi * xv + lr * si + li * sr;
            sr = nr; si = ni;
        }
        Ab[0]   = sr;
        Ab[512] = si;
        Ab += 8 * KA;
    }
}

// ---------------------------------------------------------------------------
// K5: out[(b*T+t)*128 + m] = sum_c A[(t*8+b), c] * W[c, m] + Do[m]
// (unchanged from R1 — known correct; optimize next round with counters)
// ---------------------------------------------------------------------------
#define BM 64
#define BK 32
__global__ __launch_bounds__(256) void k_gemm(const float* __restrict__ A,
                                              const float* __restrict__ W,
                                              const float* __restrict__ Do,
                                              float* __restrict__ out) {
    __shared__ float As[BM * 33];     // +1 pad
    __shared__ float Ws[BK * M_];
    int tid = threadIdx.x;
    int rl = tid & 15;                // row lane
    int cl = tid >> 4;                // col lane: cols cl*8..cl*8+7
    int row0 = blockIdx.x * BM;

    float acc[4][8];
    #pragma unroll
    for (int i = 0; i < 4; ++i)
        #pragma unroll
        for (int jj = 0; jj < 8; ++jj) acc[i][jj] = 0.f;

    for (int k0 = 0; k0 < KA; k0 += BK) {
        {
            int arow = tid >> 2;
            int acol = (tid & 3) * 8;
            const float* src = A + (size_t)(row0 + arow) * KA + k0 + acol;
            float* dst = As + arow * 33 + acol;
            float4 v0 = *(const float4*)(src);
            float4 v1 = *(const float4*)(src + 4);
            dst[0] = v0.x; dst[1] = v0.y; dst[2] = v0.z; dst[3] = v0.w;
            dst[4] = v1.x; dst[5] = v1.y; dst[6] = v1.z; dst[7] = v1.w;
        }
        {
            int idx = tid * 16;
            int wrow = idx >> 7;
            int wcol = idx & 127;
            const float* src = W + (size_t)(k0 + wrow) * M_ + wcol;
            float* dst = Ws + wrow * M_ + wcol;
            #pragma unroll
            for (int u = 0; u < 16; u += 4)
                *(float4*)(dst + u) = *(const float4*)(src + u);
        }
        __syncthreads();
        #pragma unroll 4
        for (int kk = 0; kk < BK; ++kk) {
            float a[4], w[8];
            #pragma unroll
            for (int i = 0; i < 4; ++i) a[i] = As[(rl + 16 * i) * 33 + kk];
            float4 w0 = *(const float4*)(Ws + kk * M_ + cl * 8);
            float4 w1 = *(const float4*)(Ws + kk * M_ + cl * 8 + 4);
            w[0]=w0.x; w[1]=w0.y; w[2]=w0.z; w[3]=w0.w;
            w[4]=w1.x; w[5]=w1.y; w[6]=w1.z; w[7]=w1.w;
            #pragma unroll
            for (int i = 0; i < 4; ++i)
                #pragma unroll
                for (int jj = 0; jj < 8; ++jj) acc[i][jj] += a[i] * w[jj];
        }
        __syncthreads();
    }

    float dov[8];
    #pragma unroll
    for (int u = 0; u < 8; ++u) dov[u] = Do[cl * 8 + u];

    #pragma unroll
    for (int i = 0; i < 4; ++i) {
        int r = row0 + rl + 16 * i;
        int b = r & 7, t = r >> 3;
        float* o = out + ((size_t)(b * T_ + t)) * M_ + cl * 8;
        float4 s0, s1;
        s0.x = acc[i][0] + dov[0]; s0.y = acc[i][1] + dov[1];
        s0.z = acc[i][2] + dov[2]; s0.w = acc[i][3] + dov[3];
        s1.x = acc[i][4] + dov[4]; s1.y = acc[i][5] + dov[5];
        s1.z = acc[i][6] + dov[6]; s1.w = acc[i][7] + dov[7];
        *(float4*)(o) = s0;
        *(float4*)(o + 4) = s1;
    }
}

// ---------------------------------------------------------------------------
extern "C" void kernel_launch(void* const* d_in, const int* in_sizes, int n_in,
                              void* d_out, int out_size, void* d_ws, size_t ws_size,
                              hipStream_t stream) {
    const float* x     = (const float*)d_in[0];
    const float* R     = (const float*)d_in[1];
    const float* theta = (const float*)d_in[2];
    const float* lnC_r = (const float*)d_in[3];
    const float* lnC_i = (const float*)d_in[4];
    const float* D     = (const float*)d_in[5];
    const float* Do    = (const float*)d_in[6];
    float* out = (float*)d_out;

    float* wsf   = (float*)d_ws;
    float* lambp = wsf;                        // 2048 floats
    float* W     = wsf + 2048;                 // 135168 floats
    float* xp    = W + (size_t)KA * M_;        // 524288 floats
    float* A     = xp + (size_t)BT * K_;       // 17301504 floats
    float* E     = A + (size_t)BT * KA;        // 262144 floats (Re+Im)
    float* S     = E + 2 * (size_t)NSC;        // 262144 floats (Re+Im)

    k_lambp<<<1, 512, 0, stream>>>(theta, lambp);
    k_weights<<<272, 256, 0, stream>>>(lnC_r, lnC_i, D, W);
    k_xp<<<BT / 8, 256, 0, stream>>>(x, R, xp, A);
    k_scan_ends<<<NSC / 256, 256, 0, stream>>>(xp, lambp, E);
    k_carries<<<16, 256, 0, stream>>>(lambp, E, S);
    k_scan_write<<<NSC / 256, 256, 0, stream>>>(xp, lambp, S, A);
    k_gemm<<<BT / BM, 256, 0, stream>>>(A, W, Do, out);
}

// Round 3
// 201.809 us; speedup vs baseline: 3.5065x; 1.2279x over previous
//
#include <hip/hip_runtime.h>
#include <math.h>

// Problem constants
#define K_  32
#define HN  16      // n/2
#define N_  32
#define M_  128
#define B_  8
#define T_  2048
#define D_  128
#define BT  (B_*T_)     // 16384
#define KA  1056        // GEMM K: 512 Re(s) + 512 Im(s) + 32 xp
#define CHK 32          // chunks per series
#define CL  64          // chunk length (T/CHK)
#define NSER (B_*K_*HN) // 4096 series
#define NSC  (NSER*CHK) // 131072 series-chunks
#define KSLC 352        // split-K slice (3 x 352 = 1056), 11 BK-iters each

// ---------------------------------------------------------------------------
// K1: lambda (j<16) and Bp (j<16) via direct complex product.
// ws layout (floats): [0..512) lamRe, [512..1024) lamIm,
//                     [1024..1536) BpRe, [1536..2048) BpIm
// ---------------------------------------------------------------------------
__global__ void k_lambp(const float* __restrict__ theta, float* __restrict__ ws) {
    int tid = threadIdx.x;            // 512 threads: k*16 + j
    int k = tid >> 4, j = tid & 15;
    float angj = theta[k * HN + j];
    float pr = 1.f, pi = 0.f;
    for (int i = 0; i < N_; ++i) {
        if (i == j) continue;
        float angi = (i < HN) ? theta[k * HN + i] : -theta[k * HN + i - HN];
        float d = angi - angj;
        float tr = 1.f - cosf(d);
        float ti = -sinf(d);
        float nr = pr * tr - pi * ti;
        float ni = pr * ti + pi * tr;
        pr = nr; pi = ni;
    }
    float den = pr * pr + pi * pi;
    ws[tid]        = cosf(angj);
    ws[512 + tid]  = sinf(angj);
    ws[1024 + tid] = pr / den;
    ws[1536 + tid] = -pi / den;
}

// ---------------------------------------------------------------------------
// K2: build GEMM weight matrix W [1056 x 128].
// ---------------------------------------------------------------------------
__global__ void k_weights(const float* __restrict__ lnC_r,
                          const float* __restrict__ lnC_i,
                          const float* __restrict__ D,
                          float* __restrict__ W) {
    int t = blockIdx.x * blockDim.x + threadIdx.x;
    const float inv = 1.f / 32.f;
    if (t < K_ * HN * M_) {                 // 65536
        int m = t & 127, j = (t >> 7) & 15, k = t >> 11;
        int i0 = (k * N_ + j) * M_ + m;
        int i1 = (k * N_ + j + HN) * M_ + m;
        float r0 = expf(lnC_r[i0]), c0 = cosf(lnC_i[i0]), s0 = sinf(lnC_i[i0]);
        float r1 = expf(lnC_r[i1]), c1 = cosf(lnC_i[i1]), s1 = sinf(lnC_i[i1]);
        W[(k * 16 + j) * M_ + m]       = (r0 * c0 + r1 * c1) * inv;
        W[(512 + k * 16 + j) * M_ + m] = (r1 * s1 - r0 * s0) * inv;
    } else if (t < K_ * HN * M_ + K_ * M_) {
        int u = t - K_ * HN * M_;
        int m = u & 127, k = u >> 7;
        W[(1024 + k) * M_ + m] = D[k * M_ + m] * inv;
    }
}

// ---------------------------------------------------------------------------
// K3: xp[b,t,k] = sum_d x[b,t,d]*R[d,k]; also scatter into A cols 1024..1055.
// ---------------------------------------------------------------------------
__global__ __launch_bounds__(256) void k_xp(const float* __restrict__ x,
                                            const float* __restrict__ R,
                                            float* __restrict__ xp,
                                            float* __restrict__ A) {
    int kk = threadIdx.x & 31;
    int r8 = threadIdx.x >> 5;
    int row = blockIdx.x * 8 + r8;          // row = b*T + t
    const float* xr = x + (size_t)row * D_;
    float acc = 0.f;
    #pragma unroll 8
    for (int i = 0; i < D_; ++i) acc += xr[i] * R[i * K_ + kk];
    xp[row * K_ + kk] = acc;
    int b = row >> 11, tt = row & 2047;
    A[(size_t)(tt * 8 + b) * KA + 1024 + kk] = acc;
}

// ---------------------------------------------------------------------------
// K4a: per-chunk local end-state. Thread = (b,k,c,j); 131072 threads.
// ---------------------------------------------------------------------------
__global__ __launch_bounds__(256) void k_scan_ends(const float* __restrict__ xp,
                                                   const float* __restrict__ ws,
                                                   float* __restrict__ E) {
    int gid = blockIdx.x * 256 + threadIdx.x;
    int j = gid & 15, c = (gid >> 4) & 31, k = (gid >> 9) & 31, b = gid >> 14;
    int col = k * 16 + j;
    float lr = ws[col], li = ws[512 + col], br = ws[1024 + col], bi = ws[1536 + col];
    float sr = 0.f, si = 0.f;
    const float* xpb = xp + (size_t)b * T_ * K_ + k;
    int t0 = c * CL;
    for (int p = 0; p < CL; ++p) {
        int t = t0 + p;
        if (t > 0) {
            float xv = xpb[(t - 1) * K_];
            float nr = br * xv + lr * sr - li * si;
            float ni = bi * xv + lr * si + li * sr;
            sr = nr; si = ni;
        }
    }
    size_t eidx = ((size_t)(b * 32 + k) * 32 + c) * 16 + j;
    E[eidx] = sr;
    E[NSC + eidx] = si;
}

// ---------------------------------------------------------------------------
// K4b: exclusive-prefix carries per series.
// ---------------------------------------------------------------------------
__global__ void k_carries(const float* __restrict__ ws,
                          const float* __restrict__ E,
                          float* __restrict__ S) {
    int tid = blockIdx.x * blockDim.x + threadIdx.x;   // 4096
    int j = tid & 15, k = (tid >> 4) & 31, b = tid >> 9;
    int col = k * 16 + j;
    float lr = ws[col], li = ws[512 + col];
    float pr = lr, pi = li;                 // lambda^64 via 6 squarings
    #pragma unroll
    for (int q = 0; q < 6; ++q) {
        float nr = pr * pr - pi * pi;
        float ni = 2.f * pr * pi;
        pr = nr; pi = ni;
    }
    float sr = 0.f, si = 0.f;
    size_t base = (size_t)(b * 32 + k) * 32 * 16 + j;
    for (int c = 0; c < CHK; ++c) {
        size_t idx = base + (size_t)c * 16;
        S[idx] = sr;
        S[NSC + idx] = si;
        float er = E[idx], ei = E[NSC + idx];
        float nr = pr * sr - pi * si + er;
        float ni = pr * si + pi * sr + ei;
        sr = nr; si = ni;
    }
}

// ---------------------------------------------------------------------------
// K4c: final chunk scan seeded with carry; writes Re/Im into A.
// ---------------------------------------------------------------------------
__global__ __launch_bounds__(256) void k_scan_write(const float* __restrict__ xp,
                                                    const float* __restrict__ ws,
                                                    const float* __restrict__ S,
                                                    float* __restrict__ A) {
    int gid = blockIdx.x * 256 + threadIdx.x;
    int j = gid & 15, c = (gid >> 4) & 31, k = (gid >> 9) & 31, b = gid >> 14;
    int col = k * 16 + j;
    float lr = ws[col], li = ws[512 + col], br = ws[1024 + col], bi = ws[1536 + col];
    size_t sidx = ((size_t)(b * 32 + k) * 32 + c) * 16 + j;
    float sr = S[sidx], si = S[NSC + sidx];
    const float* xpb = xp + (size_t)b * T_ * K_ + k;
    int t0 = c * CL;
    float* Ab = A + (size_t)(t0 * 8 + b) * KA + col;
    for (int p = 0; p < CL; ++p) {
        int t = t0 + p;
        if (t > 0) {
            float xv = xpb[(t - 1) * K_];
            float nr = br * xv + lr * sr - li * si;
            float ni = bi * xv + lr * si + li * sr;
            sr = nr; si = ni;
        }
        Ab[0]   = sr;
        Ab[512] = si;
        Ab += 8 * KA;
    }
}

// ---------------------------------------------------------------------------
// K5: split-K GEMM. P[ks][r][m] = sum_{c in slice ks} A[r,c] * W[c,m]
// BM=64, BN=128, BK=32, splitK=3 (slices of 352 = 11 iters).
// 768 blocks x 128 threads. Per-thread 8x8 register tile.
// Thread map: rl = tid>>4 (0..7) -> rows rl+8i; cl = tid&15 -> cols
// {cl*4..cl*4+3} and {64+cl*4..64+cl*4+3}.
// ---------------------------------------------------------------------------
#define BM 64
#define BK 32
__global__ __launch_bounds__(128, 2) void k_gemm(const float* __restrict__ A,
                                                 const float* __restrict__ W,
                                                 float* __restrict__ P) {
    __shared__ float As[BM * 33];          // padded rows (+1)
    __shared__ float Ws[BK * M_];          // 16 KB, contiguous copy of W slice
    int tid = threadIdx.x;
    int rt = blockIdx.x & 255;
    int ks = blockIdx.x >> 8;
    int row0 = rt * BM;
    int kbase = ks * KSLC;

    int rl = tid >> 4;                     // 0..7
    int cl = tid & 15;                     // 0..15

    float acc[8][8];
    #pragma unroll
    for (int i = 0; i < 8; ++i)
        #pragma unroll
        for (int d = 0; d < 8; ++d) acc[i][d] = 0.f;

    int arow = tid >> 1;                   // 0..63
    int acol = (tid & 1) * 16;

    for (int it = 0; it < 11; ++it) {
        int k0 = kbase + it * BK;
        // --- stage A tile: 64 rows x 32 cols, 16 floats/thread ---
        {
            const float* src = A + (size_t)(row0 + arow) * KA + k0 + acol;
            float* dst = As + arow * 33 + acol;
            #pragma unroll
            for (int u = 0; u < 16; u += 4) {
                float4 v = *(const float4*)(src + u);
                dst[u] = v.x; dst[u+1] = v.y; dst[u+2] = v.z; dst[u+3] = v.w;
            }
        }
        // --- stage W tile: contiguous 4096 floats, lane-consecutive float4 ---
        {
            const float4* src4 = (const float4*)(W + (size_t)k0 * M_);
            float4* dst4 = (float4*)Ws;
            #pragma unroll
            for (int u = 0; u < 8; ++u)
                dst4[u * 128 + tid] = src4[u * 128 + tid];
        }
        __syncthreads();
        #pragma unroll 2
        for (int kk = 0; kk < BK; ++kk) {
            float a[8];
            #pragma unroll
            for (int i = 0; i < 8; ++i) a[i] = As[(rl + 8 * i) * 33 + kk];
            float4 w0 = *(const float4*)(Ws + kk * M_ + cl * 4);
            float4 w1 = *(const float4*)(Ws + kk * M_ + 64 + cl * 4);
            #pragma unroll
            for (int i = 0; i < 8; ++i) {
                acc[i][0] += a[i] * w0.x; acc[i][1] += a[i] * w0.y;
                acc[i][2] += a[i] * w0.z; acc[i][3] += a[i] * w0.w;
                acc[i][4] += a[i] * w1.x; acc[i][5] += a[i] * w1.y;
                acc[i][6] += a[i] * w1.z; acc[i][7] += a[i] * w1.w;
            }
        }
        __syncthreads();
    }

    float* Pb = P + ((size_t)ks * BT + row0) * M_;
    #pragma unroll
    for (int i = 0; i < 8; ++i) {
        int r = rl + 8 * i;
        float4 s0, s1;
        s0.x = acc[i][0]; s0.y = acc[i][1]; s0.z = acc[i][2]; s0.w = acc[i][3];
        s1.x = acc[i][4]; s1.y = acc[i][5]; s1.z = acc[i][6]; s1.w = acc[i][7];
        *(float4*)(Pb + (size_t)r * M_ + cl * 4) = s0;
        *(float4*)(Pb + (size_t)r * M_ + 64 + cl * 4) = s1;
    }
}

// ---------------------------------------------------------------------------
// K6: reduce split-K partials + Do, permute r=t*8+b -> out row b*T+t.
// ---------------------------------------------------------------------------
__global__ __launch_bounds__(256) void k_red(const float* __restrict__ P,
                                             const float* __restrict__ Do,
                                             float* __restrict__ out) {
    int g = blockIdx.x * 256 + threadIdx.x;      // float4 index, 524288 total
    int r = g >> 5, c4 = g & 31;
    const float4* P4 = (const float4*)P;
    float4 v0 = P4[g];
    float4 v1 = P4[(size_t)BT * 32 + g];
    float4 v2 = P4[(size_t)2 * BT * 32 + g];
    float4 dv = ((const float4*)Do)[c4];
    int b = r & 7, t = r >> 3;
    float4 o;
    o.x = v0.x + v1.x + v2.x + dv.x;
    o.y = v0.y + v1.y + v2.y + dv.y;
    o.z = v0.z + v1.z + v2.z + dv.z;
    o.w = v0.w + v1.w + v2.w + dv.w;
    ((float4*)out)[(size_t)(b * T_ + t) * 32 + c4] = o;
}

// ---------------------------------------------------------------------------
extern "C" void kernel_launch(void* const* d_in, const int* in_sizes, int n_in,
                              void* d_out, int out_size, void* d_ws, size_t ws_size,
                              hipStream_t stream) {
    const float* x     = (const float*)d_in[0];
    const float* R     = (const float*)d_in[1];
    const float* theta = (const float*)d_in[2];
    const float* lnC_r = (const float*)d_in[3];
    const float* lnC_i = (const float*)d_in[4];
    const float* D     = (const float*)d_in[5];
    const float* Do    = (const float*)d_in[6];
    float* out = (float*)d_out;

    float* wsf   = (float*)d_ws;
    float* lambp = wsf;                        // 2048 floats
    float* W     = wsf + 2048;                 // 135168 floats
    float* xp    = W + (size_t)KA * M_;        // 524288 floats
    float* A     = xp + (size_t)BT * K_;       // 17301504 floats
    float* E     = A + (size_t)BT * KA;        // 262144 floats (Re+Im)
    float* S     = E + 2 * (size_t)NSC;        // 262144 floats (Re+Im)
    float* P     = S + 2 * (size_t)NSC;        // 3*BT*128 = 6291456 floats

    k_lambp<<<1, 512, 0, stream>>>(theta, lambp);
    k_weights<<<272, 256, 0, stream>>>(lnC_r, lnC_i, D, W);
    k_xp<<<BT / 8, 256, 0, stream>>>(x, R, xp, A);
    k_scan_ends<<<NSC / 256, 256, 0, stream>>>(xp, lambp, E);
    k_carries<<<16, 256, 0, stream>>>(lambp, E, S);
    k_scan_write<<<NSC / 256, 256, 0, stream>>>(xp, lambp, S, A);
    k_gemm<<<768, 128, 0, stream>>>(A, W, P);
    k_red<<<BT * M_ / 4 / 256, 256, 0, stream>>>(P, Do, out);
}